// Round 3
// baseline (1935.853 us; speedup 1.0000x reference)
//
#include <hip/hip_runtime.h>

#define NPTS 16384
#define KNN 16
#define HID 64
#define NCLS 10

#define CHUNKS_T 16
#define CHUNK_T (NPTS / CHUNKS_T)   // 1024
#define NSTR 16                     // streams for tau bound
#define CHUNKS_S 32
#define CHUNK_S (NPTS / CHUNKS_S)   // 512
#define CAPS 12                     // survivor slots per (query, chunk)

// distance helper: identical fmaf chain in every kernel so τ comparisons are
// bit-exact across passes (drop sq_i: rank-invariant per query)
__device__ __forceinline__ float distf(float4 q, float4 p) {
    float dot = fmaf(q.x, p.x, fmaf(q.y, p.y, q.z * p.z));
    return fmaf(-2.f, dot, p.w);
}

// pos (N,3) -> pos4 (x,y,z,|p|^2)
__global__ void prep_kernel(const float* __restrict__ pos, float4* __restrict__ pos4) {
    int i = blockIdx.x * 256 + threadIdx.x;
    if (i < NPTS) {
        float x = pos[3 * i], y = pos[3 * i + 1], z = pos[3 * i + 2];
        pos4[i] = make_float4(x, y, z, fmaf(x, x, fmaf(y, y, z * z)));
    }
}

// Pass 1: per (query, chunk): NSTR stream minima (stream = j mod NSTR).
// Branchless; LDS tile broadcast for candidates; 16 waves/CU.
__global__ __launch_bounds__(256) void knn_tau_kernel(const float4* __restrict__ pos4,
                                                      float* __restrict__ minpart) {
    int q = blockIdx.x * 256 + threadIdx.x;
    int c = blockIdx.y;
    float4 qp = pos4[q];
    float mn[NSTR];
#pragma unroll
    for (int u = 0; u < NSTR; ++u) mn[u] = INFINITY;
    __shared__ float4 tile[256];
    int base = c * CHUNK_T;
    for (int t0 = 0; t0 < CHUNK_T; t0 += 256) {
        __syncthreads();
        tile[threadIdx.x] = pos4[base + t0 + threadIdx.x];
        __syncthreads();
        for (int jj = 0; jj < 256; jj += NSTR) {
#pragma unroll
            for (int u = 0; u < NSTR; ++u) {
                float d = distf(qp, tile[jj + u]);  // broadcast ds_read
                mn[u] = fminf(mn[u], d);
            }
        }
    }
#pragma unroll
    for (int u = 0; u < NSTR; ++u) minpart[(c * NSTR + u) * NPTS + q] = mn[u];
}

// tau[q] = max over the 16 global stream minima. Guaranteed >= d_16(q):
// the 16 stream argmins are distinct indices, all with d <= tau.
__global__ __launch_bounds__(256) void knn_tau_reduce_kernel(const float* __restrict__ minpart,
                                                             float* __restrict__ tau) {
    int q = blockIdx.x * 256 + threadIdx.x;
    float t = -INFINITY;
#pragma unroll
    for (int u = 0; u < NSTR; ++u) {
        float m = INFINITY;
#pragma unroll
        for (int c = 0; c < CHUNKS_T; ++c) m = fminf(m, minpart[(c * NSTR + u) * NPTS + q]);
        t = fmaxf(t, m);
    }
    tau[q] = t;
}

// Pass 2: record tau-survivor indices per (query, chunk). No sorting, no atomics.
// 2048 blocks -> 32 waves/CU (100% occupancy); branch body is ~6 inst.
__global__ __launch_bounds__(256) void knn_survey_kernel(const float4* __restrict__ pos4,
                                                         const float* __restrict__ tau,
                                                         int* __restrict__ surv,
                                                         int* __restrict__ cnt,
                                                         int* __restrict__ flags) {
    int q = blockIdx.x * 256 + threadIdx.x;
    int c = blockIdx.y;
    float4 qp = pos4[q];
    float tq = tau[q];
    __shared__ float4 tile[256];
    int base = c * CHUNK_S;
    int cr = 0;
    int sbase = (q * CHUNKS_S + c) * CAPS;
    for (int t0 = 0; t0 < CHUNK_S; t0 += 256) {
        __syncthreads();
        tile[threadIdx.x] = pos4[base + t0 + threadIdx.x];
        __syncthreads();
#pragma unroll 4
        for (int jj = 0; jj < 256; ++jj) {
            float v = distf(qp, tile[jj]);
            if (v <= tq) {
                if (cr < CAPS) surv[sbase + cr] = base + t0 + jj;
                ++cr;
            }
        }
    }
    cnt[c * NPTS + q] = cr;
    if (cr > CAPS) flags[q] = 1;   // overflow -> exact rescan in final (P ~ 2e-3/run)
}

__device__ __forceinline__ void insert16(float v, int vi, float d[16], int id[16]) {
    // tie-break on lower index to match lax.top_k
    float cv = v; int ci = vi;
#pragma unroll
    for (int s = 0; s < 16; ++s) {
        bool sw = (cv < d[s]) || (cv == d[s] && ci < id[s]);
        float td = d[s]; int ti = id[s];
        if (sw) { d[s] = cv; id[s] = ci; cv = td; ci = ti; }
    }
}

// Pass 3: exact tie-broken top-16 over the ~54 survivors per query.
__global__ __launch_bounds__(64) void knn_final_kernel(const float4* __restrict__ pos4,
                                                       const int* __restrict__ surv,
                                                       const int* __restrict__ cnt,
                                                       const int* __restrict__ flags,
                                                       const float* __restrict__ tau,
                                                       int* __restrict__ idx) {
    int q = blockIdx.x * 64 + threadIdx.x;
    float4 qp = pos4[q];
    float d[16]; int id[16];
#pragma unroll
    for (int u = 0; u < 16; ++u) { d[u] = INFINITY; id[u] = 0x7fffffff; }
    if (flags[q] == 0) {
        for (int c = 0; c < CHUNKS_S; ++c) {
            int n = min(cnt[c * NPTS + q], CAPS);
            for (int s = 0; s < n; ++s) {
                int j = surv[(q * CHUNKS_S + c) * CAPS + s];
                float v = distf(qp, pos4[j]);
                if (v < d[15] || (v == d[15] && j < id[15])) insert16(v, j, d, id);
            }
        }
    } else {
        // overflow slow path: exact tau-filtered full rescan (expected never)
        float tq = tau[q];
        for (int j = 0; j < NPTS; ++j) {
            float v = distf(qp, pos4[j]);
            if (v <= tq && (v < d[15] || (v == d[15] && j < id[15]))) insert16(v, j, d, id);
        }
    }
#pragma unroll
    for (int u = 0; u < 16; ++u) idx[q * KNN + u] = id[u];
}

// EdgeConv1: pos (F=3) -> h1 (64). m[t] = b1 + sum_f xi_f*(W1[f][t]-W1[3+f][t]) + sum_f xj_f*W1[3+f][t]
__global__ __launch_bounds__(256) void ec1_kernel(const float4* __restrict__ pos4,
                                                  const int* __restrict__ idx,
                                                  const float* __restrict__ W1,
                                                  const float* __restrict__ b1,
                                                  float* __restrict__ h1) {
    int t = threadIdx.x & 63;
    int p = blockIdx.x * 4 + (threadIdx.x >> 6);
    float4 xi = pos4[p];
    float w0 = W1[0 * HID + t], w1 = W1[1 * HID + t], w2 = W1[2 * HID + t];
    float v0 = W1[3 * HID + t], v1 = W1[4 * HID + t], v2 = W1[5 * HID + t];
    float C = b1[t] + xi.x * (w0 - v0) + xi.y * (w1 - v1) + xi.z * (w2 - v2);
    float m = -INFINITY;
#pragma unroll
    for (int k = 0; k < KNN; ++k) {
        int j = idx[p * KNN + k];
        float4 xj = pos4[j];
        float a = C + xj.x * v0 + xj.y * v1 + xj.z * v2;
        m = fmaxf(m, a);
    }
    h1[p * HID + t] = fmaxf(m, 0.f);
}

// EdgeConv2 fused with per-block partial max-pool.
__global__ __launch_bounds__(256) void ec2_kernel(const float* __restrict__ h1,
                                                  const int* __restrict__ idx,
                                                  const float* __restrict__ W2,
                                                  const float* __restrict__ b2,
                                                  float* __restrict__ gpartial) {
    int t = threadIdx.x & 63;
    int lp = threadIdx.x >> 6;
    int p = blockIdx.x * 4 + lp;
    float wb[64];
#pragma unroll
    for (int f = 0; f < 64; ++f) wb[f] = W2[(64 + f) * HID + t];
    float C = b2[t];
    const float4* h14 = (const float4*)h1;
#pragma unroll
    for (int f4 = 0; f4 < 16; ++f4) {
        float4 hv = h14[p * 16 + f4];
        C += hv.x * (W2[(f4 * 4 + 0) * HID + t] - wb[f4 * 4 + 0]);
        C += hv.y * (W2[(f4 * 4 + 1) * HID + t] - wb[f4 * 4 + 1]);
        C += hv.z * (W2[(f4 * 4 + 2) * HID + t] - wb[f4 * 4 + 2]);
        C += hv.w * (W2[(f4 * 4 + 3) * HID + t] - wb[f4 * 4 + 3]);
    }
    float m = -INFINITY;
    for (int k = 0; k < KNN; ++k) {
        int j = idx[p * KNN + k];
        float acc = C;
#pragma unroll
        for (int f4 = 0; f4 < 16; ++f4) {
            float4 hv = h14[j * 16 + f4];
            acc = fmaf(hv.x, wb[f4 * 4 + 0], acc);
            acc = fmaf(hv.y, wb[f4 * 4 + 1], acc);
            acc = fmaf(hv.z, wb[f4 * 4 + 2], acc);
            acc = fmaf(hv.w, wb[f4 * 4 + 3], acc);
        }
        m = fmaxf(m, acc);
    }
    m = fmaxf(m, 0.f);
    __shared__ float red[4][64];
    red[lp][t] = m;
    __syncthreads();
    if (lp == 0) {
        float g = fmaxf(fmaxf(red[0][t], red[1][t]), fmaxf(red[2][t], red[3][t]));
        gpartial[blockIdx.x * 64 + t] = g;
    }
}

__global__ void greduce_kernel(const float* __restrict__ gpartial, float* __restrict__ g, int nb) {
    int f = blockIdx.x;
    float m = -INFINITY;
    for (int i = threadIdx.x; i < nb; i += 256) m = fmaxf(m, gpartial[i * 64 + f]);
    __shared__ float s[256];
    s[threadIdx.x] = m;
    __syncthreads();
    for (int st = 128; st > 0; st >>= 1) {
        if (threadIdx.x < st) s[threadIdx.x] = fmaxf(s[threadIdx.x], s[threadIdx.x + st]);
        __syncthreads();
    }
    if (threadIdx.x == 0) g[f] = s[0];
}

__global__ void head_kernel(const float* __restrict__ g, const float* __restrict__ Wc,
                            const float* __restrict__ bc, float* __restrict__ out) {
    int c = threadIdx.x;
    if (c < NCLS) {
        float a = bc[c];
#pragma unroll
        for (int h = 0; h < HID; ++h) a = fmaf(g[h], Wc[h * NCLS + c], a);
        out[c] = a;
    }
}

extern "C" void kernel_launch(void* const* d_in, const int* in_sizes, int n_in,
                              void* d_out, int out_size, void* d_ws, size_t ws_size,
                              hipStream_t stream) {
    const float* pos = (const float*)d_in[0];
    // d_in[1] = batch (all zeros, num_segments=1) -> unused
    const float* W1 = (const float*)d_in[2];
    const float* b1 = (const float*)d_in[3];
    const float* W2 = (const float*)d_in[4];
    const float* b2 = (const float*)d_in[5];
    const float* Wc = (const float*)d_in[6];
    const float* bc = (const float*)d_in[7];
    float* out = (float*)d_out;

    char* ws = (char*)d_ws;
    size_t o = 0;
    auto alloc = [&](size_t bytes) { size_t r = o; o += (bytes + 255) & ~size_t(255); return r; };
    size_t sz_minp = (size_t)NPTS * CHUNKS_T * NSTR * 4;      // 16MB
    size_t sz_surv = (size_t)NPTS * CHUNKS_S * CAPS * 4;      // 24MB
    size_t o_pos4 = alloc((size_t)NPTS * 16);
    size_t o_shared = alloc(sz_minp > sz_surv ? sz_minp : sz_surv);  // minpart, later surv
    size_t o_tau = alloc((size_t)NPTS * 4);
    size_t o_cnt = alloc((size_t)NPTS * CHUNKS_S * 4);
    size_t o_flag = alloc((size_t)NPTS * 4);
    size_t o_idx = alloc((size_t)NPTS * KNN * 4);
    size_t o_h1 = alloc((size_t)NPTS * HID * 4);
    size_t o_gp = alloc((size_t)(NPTS / 4) * HID * 4);
    size_t o_g = alloc(256);

    float4* pos4 = (float4*)(ws + o_pos4);
    float* minp = (float*)(ws + o_shared);
    int* surv = (int*)(ws + o_shared);    // overlays minpart (dead after tau_reduce)
    float* tau = (float*)(ws + o_tau);
    int* cnt = (int*)(ws + o_cnt);
    int* flags = (int*)(ws + o_flag);
    int* idx = (int*)(ws + o_idx);
    float* h1 = (float*)(ws + o_h1);
    float* gp = (float*)(ws + o_gp);
    float* g = (float*)(ws + o_g);

    hipMemsetAsync(flags, 0, (size_t)NPTS * 4, stream);

    prep_kernel<<<NPTS / 256, 256, 0, stream>>>(pos, pos4);
    knn_tau_kernel<<<dim3(NPTS / 256, CHUNKS_T), 256, 0, stream>>>(pos4, minp);
    knn_tau_reduce_kernel<<<NPTS / 256, 256, 0, stream>>>(minp, tau);
    knn_survey_kernel<<<dim3(NPTS / 256, CHUNKS_S), 256, 0, stream>>>(pos4, tau, surv, cnt, flags);
    knn_final_kernel<<<NPTS / 64, 64, 0, stream>>>(pos4, surv, cnt, flags, tau, idx);
    ec1_kernel<<<NPTS / 4, 256, 0, stream>>>(pos4, idx, W1, b1, h1);
    ec2_kernel<<<NPTS / 4, 256, 0, stream>>>(h1, idx, W2, b2, gp);
    greduce_kernel<<<HID, 256, 0, stream>>>(gp, g, NPTS / 4);
    head_kernel<<<1, 64, 0, stream>>>(g, Wc, bc, out);
}

// Round 4
// 480.418 us; speedup vs baseline: 4.0295x; 4.0295x over previous
//
#include <hip/hip_runtime.h>

#define NPTS 16384
#define KNN 16
#define HID 64
#define NCLS 10

#define CHUNKS_T 16
#define CHUNK_T (NPTS / CHUNKS_T)   // 1024
#define NSTR 16                     // streams for tau bound
#define CHUNKS_S 32
#define CHUNK_S (NPTS / CHUNKS_S)   // 512
#define CAPS 12                     // survivor slots per (query, chunk)

// distance helper: identical fmaf chain in every kernel so τ comparisons are
// bit-exact across passes (drop sq_i: rank-invariant per query)
__device__ __forceinline__ float distf(float4 q, float4 p) {
    float dot = fmaf(q.x, p.x, fmaf(q.y, p.y, q.z * p.z));
    return fmaf(-2.f, dot, p.w);
}

// monotone float->u32, packed with index: ascending u64 order == (d asc, j asc)
__device__ __forceinline__ unsigned long long dkey(float v, int j) {
    unsigned u = __float_as_uint(v);
    u = (u & 0x80000000u) ? ~u : (u | 0x80000000u);
    return ((unsigned long long)u << 32) | (unsigned)j;
}

__device__ __forceinline__ unsigned long long shfl_xor_u64(unsigned long long x, int m) {
    unsigned hi = (unsigned)__shfl_xor((int)(x >> 32), m, 64);
    unsigned lo = (unsigned)__shfl_xor((int)(x & 0xffffffffu), m, 64);
    return ((unsigned long long)hi << 32) | lo;
}

// exact wave-wide top-16 extraction from NS keys/lane (keys unique or ~0ull pad)
template <int NS>
__device__ __forceinline__ void wave_top16(unsigned long long (&key)[NS], int lane,
                                           int q, int* __restrict__ idx) {
    int outj = 0x7fffffff;
    for (int r = 0; r < 16; ++r) {
        unsigned long long gm = key[0];
#pragma unroll
        for (int s = 1; s < NS; ++s) gm = key[s] < gm ? key[s] : gm;
#pragma unroll
        for (int st = 1; st < 64; st <<= 1) {
            unsigned long long o = shfl_xor_u64(gm, st);
            gm = o < gm ? o : gm;
        }
        if (lane == r) outj = (int)(gm & 0xffffffffu);
#pragma unroll
        for (int s = 0; s < NS; ++s)
            if (key[s] == gm) key[s] = ~0ull;
    }
    if (lane < 16) idx[q * KNN + lane] = outj;
}

// pos (N,3) -> pos4 (x,y,z,|p|^2)
__global__ void prep_kernel(const float* __restrict__ pos, float4* __restrict__ pos4) {
    int i = blockIdx.x * 256 + threadIdx.x;
    if (i < NPTS) {
        float x = pos[3 * i], y = pos[3 * i + 1], z = pos[3 * i + 2];
        pos4[i] = make_float4(x, y, z, fmaf(x, x, fmaf(y, y, z * z)));
    }
}

// Pass 1: NSTR stream minima per (query, chunk); 2 queries per thread so each
// ds_read_b128 serves 10 VALU ops (LDS pipe was the Q=1 bottleneck).
__global__ __launch_bounds__(256) void knn_tau_kernel(const float4* __restrict__ pos4,
                                                      float* __restrict__ minpart) {
    int tid = threadIdx.x;
    int q0 = blockIdx.x * 512 + tid;
    int q1 = q0 + 256;
    int c = blockIdx.y;
    float4 qa = pos4[q0];
    float4 qb = pos4[q1];
    float mna[NSTR], mnb[NSTR];
#pragma unroll
    for (int u = 0; u < NSTR; ++u) { mna[u] = INFINITY; mnb[u] = INFINITY; }
    __shared__ float4 tile[256];
    int base = c * CHUNK_T;
    for (int t0 = 0; t0 < CHUNK_T; t0 += 256) {
        __syncthreads();
        tile[tid] = pos4[base + t0 + tid];
        __syncthreads();
        for (int jj = 0; jj < 256; jj += NSTR) {
#pragma unroll
            for (int u = 0; u < NSTR; ++u) {
                float4 p = tile[jj + u];
                mna[u] = fminf(mna[u], distf(qa, p));
                mnb[u] = fminf(mnb[u], distf(qb, p));
            }
        }
    }
#pragma unroll
    for (int u = 0; u < NSTR; ++u) {
        minpart[(c * NSTR + u) * NPTS + q0] = mna[u];
        minpart[(c * NSTR + u) * NPTS + q1] = mnb[u];
    }
}

// tau[q] = max over the 16 global stream minima; >= d_16(q) (16 distinct argmins).
__global__ __launch_bounds__(256) void knn_tau_reduce_kernel(const float* __restrict__ minpart,
                                                             float* __restrict__ tau) {
    int q = blockIdx.x * 256 + threadIdx.x;
    float t = -INFINITY;
#pragma unroll
    for (int u = 0; u < NSTR; ++u) {
        float m = INFINITY;
#pragma unroll
        for (int c = 0; c < CHUNKS_T; ++c) m = fminf(m, minpart[(c * NSTR + u) * NPTS + q]);
        t = fmaxf(t, m);
    }
    tau[q] = t;
}

// Pass 2: record tau-survivor indices per (query, chunk); 2 queries/thread.
__global__ __launch_bounds__(256) void knn_survey_kernel(const float4* __restrict__ pos4,
                                                         const float* __restrict__ tau,
                                                         int* __restrict__ surv,
                                                         int* __restrict__ cnt,
                                                         int* __restrict__ flags) {
    int tid = threadIdx.x;
    int q0 = blockIdx.x * 512 + tid;
    int q1 = q0 + 256;
    int c = blockIdx.y;
    float4 qa = pos4[q0];
    float4 qb = pos4[q1];
    float ta = tau[q0];
    float tb = tau[q1];
    __shared__ float4 tile[256];
    int base = c * CHUNK_S;
    int ca = 0, cb = 0;
    int sba = (q0 * CHUNKS_S + c) * CAPS;
    int sbb = (q1 * CHUNKS_S + c) * CAPS;
    for (int t0 = 0; t0 < CHUNK_S; t0 += 256) {
        __syncthreads();
        tile[tid] = pos4[base + t0 + tid];
        __syncthreads();
#pragma unroll 4
        for (int jj = 0; jj < 256; ++jj) {
            float4 p = tile[jj];
            float va = distf(qa, p);
            float vb = distf(qb, p);
            if (va <= ta) {
                if (ca < CAPS) surv[sba + ca] = base + t0 + jj;
                ++ca;
            }
            if (vb <= tb) {
                if (cb < CAPS) surv[sbb + cb] = base + t0 + jj;
                ++cb;
            }
        }
    }
    cnt[c * NPTS + q0] = ca;
    cnt[c * NPTS + q1] = cb;
    if (ca > CAPS) flags[q0] = 1;
    if (cb > CAPS) flags[q1] = 1;
}

// Pass 3: ONE WAVE PER QUERY. All 384 survivor slots loaded in parallel across
// lanes; exact top-16 via packed-u64 wave merge.
__global__ __launch_bounds__(256) void knn_final_kernel(const float4* __restrict__ pos4,
                                                        const int* __restrict__ surv,
                                                        const int* __restrict__ cnt,
                                                        const int* __restrict__ flags,
                                                        const float* __restrict__ tau,
                                                        int* __restrict__ idx) {
    int lane = threadIdx.x & 63;
    int q = blockIdx.x * 4 + (threadIdx.x >> 6);
    float4 qp = pos4[q];
    if (flags[q] == 0) {
        int c = lane & 31;
        int sb = lane >> 5;                 // 0 or 1
        int n = cnt[c * NPTS + q];
        int sbase = (q * CHUNKS_S + c) * CAPS;
        unsigned long long key[6];
#pragma unroll
        for (int r = 0; r < 6; ++r) {
            int s = sb + 2 * r;             // slots 0..11
            key[r] = ~0ull;
            if (s < n) {
                int j = surv[sbase + s];
                key[r] = dkey(distf(qp, pos4[j]), j);
            }
        }
        wave_top16<6>(key, lane, q, idx);
    } else {
        // overflow slow path (P ~ 1e-2 per RUN): wave-cooperative exact rescan
        float tq = tau[q];
        unsigned long long key[16];
#pragma unroll
        for (int u = 0; u < 16; ++u) key[u] = ~0ull;
        for (int j = lane; j < NPTS; j += 64) {
            float v = distf(qp, pos4[j]);
            unsigned long long k = dkey(v, j);
            if (v <= tq && k < key[15]) {
#pragma unroll
                for (int s = 0; s < 16; ++s) {
                    unsigned long long mn = k < key[s] ? k : key[s];
                    unsigned long long mx = k < key[s] ? key[s] : k;
                    key[s] = mn;
                    k = mx;
                }
            }
        }
        wave_top16<16>(key, lane, q, idx);
    }
}

// EdgeConv1: pos (F=3) -> h1 (64). m[t] = C_t + sum_f xj_f*W1[3+f][t]
__global__ __launch_bounds__(256) void ec1_kernel(const float4* __restrict__ pos4,
                                                  const int* __restrict__ idx,
                                                  const float* __restrict__ W1,
                                                  const float* __restrict__ b1,
                                                  float* __restrict__ h1) {
    int t = threadIdx.x & 63;
    int p = blockIdx.x * 4 + (threadIdx.x >> 6);
    float4 xi = pos4[p];
    float w0 = W1[0 * HID + t], w1 = W1[1 * HID + t], w2 = W1[2 * HID + t];
    float v0 = W1[3 * HID + t], v1 = W1[4 * HID + t], v2 = W1[5 * HID + t];
    float C = b1[t] + xi.x * (w0 - v0) + xi.y * (w1 - v1) + xi.z * (w2 - v2);
    float m = -INFINITY;
#pragma unroll
    for (int k = 0; k < KNN; ++k) {
        int j = idx[p * KNN + k];
        float4 xj = pos4[j];
        float a = C + xj.x * v0 + xj.y * v1 + xj.z * v2;
        m = fmaxf(m, a);
    }
    h1[p * HID + t] = fmaxf(m, 0.f);
}

// EdgeConv2 fused with per-block partial max-pool.
__global__ __launch_bounds__(256) void ec2_kernel(const float* __restrict__ h1,
                                                  const int* __restrict__ idx,
                                                  const float* __restrict__ W2,
                                                  const float* __restrict__ b2,
                                                  float* __restrict__ gpartial) {
    int t = threadIdx.x & 63;
    int lp = threadIdx.x >> 6;
    int p = blockIdx.x * 4 + lp;
    float wb[64];
#pragma unroll
    for (int f = 0; f < 64; ++f) wb[f] = W2[(64 + f) * HID + t];
    float C = b2[t];
    const float4* h14 = (const float4*)h1;
#pragma unroll
    for (int f4 = 0; f4 < 16; ++f4) {
        float4 hv = h14[p * 16 + f4];
        C += hv.x * (W2[(f4 * 4 + 0) * HID + t] - wb[f4 * 4 + 0]);
        C += hv.y * (W2[(f4 * 4 + 1) * HID + t] - wb[f4 * 4 + 1]);
        C += hv.z * (W2[(f4 * 4 + 2) * HID + t] - wb[f4 * 4 + 2]);
        C += hv.w * (W2[(f4 * 4 + 3) * HID + t] - wb[f4 * 4 + 3]);
    }
    float m = -INFINITY;
    for (int k = 0; k < KNN; ++k) {
        int j = idx[p * KNN + k];
        float acc = C;
#pragma unroll
        for (int f4 = 0; f4 < 16; ++f4) {
            float4 hv = h14[j * 16 + f4];
            acc = fmaf(hv.x, wb[f4 * 4 + 0], acc);
            acc = fmaf(hv.y, wb[f4 * 4 + 1], acc);
            acc = fmaf(hv.z, wb[f4 * 4 + 2], acc);
            acc = fmaf(hv.w, wb[f4 * 4 + 3], acc);
        }
        m = fmaxf(m, acc);
    }
    m = fmaxf(m, 0.f);
    __shared__ float red[4][64];
    red[lp][t] = m;
    __syncthreads();
    if (lp == 0) {
        float g = fmaxf(fmaxf(red[0][t], red[1][t]), fmaxf(red[2][t], red[3][t]));
        gpartial[blockIdx.x * 64 + t] = g;
    }
}

__global__ void greduce_kernel(const float* __restrict__ gpartial, float* __restrict__ g, int nb) {
    int f = blockIdx.x;
    float m = -INFINITY;
    for (int i = threadIdx.x; i < nb; i += 256) m = fmaxf(m, gpartial[i * 64 + f]);
    __shared__ float s[256];
    s[threadIdx.x] = m;
    __syncthreads();
    for (int st = 128; st > 0; st >>= 1) {
        if (threadIdx.x < st) s[threadIdx.x] = fmaxf(s[threadIdx.x], s[threadIdx.x + st]);
        __syncthreads();
    }
    if (threadIdx.x == 0) g[f] = s[0];
}

__global__ void head_kernel(const float* __restrict__ g, const float* __restrict__ Wc,
                            const float* __restrict__ bc, float* __restrict__ out) {
    int c = threadIdx.x;
    if (c < NCLS) {
        float a = bc[c];
#pragma unroll
        for (int h = 0; h < HID; ++h) a = fmaf(g[h], Wc[h * NCLS + c], a);
        out[c] = a;
    }
}

extern "C" void kernel_launch(void* const* d_in, const int* in_sizes, int n_in,
                              void* d_out, int out_size, void* d_ws, size_t ws_size,
                              hipStream_t stream) {
    const float* pos = (const float*)d_in[0];
    // d_in[1] = batch (all zeros, num_segments=1) -> unused
    const float* W1 = (const float*)d_in[2];
    const float* b1 = (const float*)d_in[3];
    const float* W2 = (const float*)d_in[4];
    const float* b2 = (const float*)d_in[5];
    const float* Wc = (const float*)d_in[6];
    const float* bc = (const float*)d_in[7];
    float* out = (float*)d_out;

    char* ws = (char*)d_ws;
    size_t o = 0;
    auto alloc = [&](size_t bytes) { size_t r = o; o += (bytes + 255) & ~size_t(255); return r; };
    size_t sz_minp = (size_t)NPTS * CHUNKS_T * NSTR * 4;      // 16MB
    size_t sz_surv = (size_t)NPTS * CHUNKS_S * CAPS * 4;      // 24MB
    size_t o_pos4 = alloc((size_t)NPTS * 16);
    size_t o_shared = alloc(sz_minp > sz_surv ? sz_minp : sz_surv);  // minpart, later surv
    size_t o_tau = alloc((size_t)NPTS * 4);
    size_t o_cnt = alloc((size_t)NPTS * CHUNKS_S * 4);
    size_t o_flag = alloc((size_t)NPTS * 4);
    size_t o_idx = alloc((size_t)NPTS * KNN * 4);
    size_t o_h1 = alloc((size_t)NPTS * HID * 4);
    size_t o_gp = alloc((size_t)(NPTS / 4) * HID * 4);
    size_t o_g = alloc(256);

    float4* pos4 = (float4*)(ws + o_pos4);
    float* minp = (float*)(ws + o_shared);
    int* surv = (int*)(ws + o_shared);    // overlays minpart (dead after tau_reduce)
    float* tau = (float*)(ws + o_tau);
    int* cnt = (int*)(ws + o_cnt);
    int* flags = (int*)(ws + o_flag);
    int* idx = (int*)(ws + o_idx);
    float* h1 = (float*)(ws + o_h1);
    float* gp = (float*)(ws + o_gp);
    float* g = (float*)(ws + o_g);

    hipMemsetAsync(flags, 0, (size_t)NPTS * 4, stream);

    prep_kernel<<<NPTS / 256, 256, 0, stream>>>(pos, pos4);
    knn_tau_kernel<<<dim3(NPTS / 512, CHUNKS_T), 256, 0, stream>>>(pos4, minp);
    knn_tau_reduce_kernel<<<NPTS / 256, 256, 0, stream>>>(minp, tau);
    knn_survey_kernel<<<dim3(NPTS / 512, CHUNKS_S), 256, 0, stream>>>(pos4, tau, surv, cnt, flags);
    knn_final_kernel<<<NPTS / 4, 256, 0, stream>>>(pos4, surv, cnt, flags, tau, idx);
    ec1_kernel<<<NPTS / 4, 256, 0, stream>>>(pos4, idx, W1, b1, h1);
    ec2_kernel<<<NPTS / 4, 256, 0, stream>>>(h1, idx, W2, b2, gp);
    greduce_kernel<<<HID, 256, 0, stream>>>(gp, g, NPTS / 4);
    head_kernel<<<1, 64, 0, stream>>>(g, Wc, bc, out);
}

// Round 5
// 417.689 us; speedup vs baseline: 4.6347x; 1.1502x over previous
//
#include <hip/hip_runtime.h>

#define NPTS 16384
#define KNN 16
#define HID 64
#define NCLS 10

#define CHUNKS_T 16
#define CHUNK_T (NPTS / CHUNKS_T)   // 1024
#define NSTR 16                     // streams for tau bound
#define CHUNKS_S 32
#define CHUNK_S (NPTS / CHUNKS_S)   // 512
#define CAPS 12                     // survivor slots per (query, chunk)

// distance helper: identical fmaf chain in every kernel so τ comparisons are
// bit-exact across passes (drop sq_i: rank-invariant per query)
__device__ __forceinline__ float distf(float4 q, float4 p) {
    float dot = fmaf(q.x, p.x, fmaf(q.y, p.y, q.z * p.z));
    return fmaf(-2.f, dot, p.w);
}

// monotone float->u32, packed with index: ascending u64 order == (d asc, j asc)
__device__ __forceinline__ unsigned long long dkey(float v, int j) {
    unsigned u = __float_as_uint(v);
    u = (u & 0x80000000u) ? ~u : (u | 0x80000000u);
    return ((unsigned long long)u << 32) | (unsigned)j;
}

__device__ __forceinline__ unsigned long long shfl_xor_u64(unsigned long long x, int m) {
    unsigned hi = (unsigned)__shfl_xor((int)(x >> 32), m, 64);
    unsigned lo = (unsigned)__shfl_xor((int)(x & 0xffffffffu), m, 64);
    return ((unsigned long long)hi << 32) | lo;
}

// exact wave-wide top-16 extraction from NS keys/lane (keys unique or ~0ull pad)
template <int NS>
__device__ __forceinline__ void wave_top16(unsigned long long (&key)[NS], int lane,
                                           int q, int* __restrict__ idx) {
    int outj = 0x7fffffff;
    for (int r = 0; r < 16; ++r) {
        unsigned long long gm = key[0];
#pragma unroll
        for (int s = 1; s < NS; ++s) gm = key[s] < gm ? key[s] : gm;
#pragma unroll
        for (int st = 1; st < 64; st <<= 1) {
            unsigned long long o = shfl_xor_u64(gm, st);
            gm = o < gm ? o : gm;
        }
        if (lane == r) outj = (int)(gm & 0xffffffffu);
#pragma unroll
        for (int s = 0; s < NS; ++s)
            if (key[s] == gm) key[s] = ~0ull;
    }
    if (lane < 16) idx[q * KNN + lane] = outj;
}

// pos (N,3) -> pos4 (x,y,z,|p|^2)
__global__ void prep_kernel(const float* __restrict__ pos, float4* __restrict__ pos4) {
    int i = blockIdx.x * 256 + threadIdx.x;
    if (i < NPTS) {
        float x = pos[3 * i], y = pos[3 * i + 1], z = pos[3 * i + 2];
        pos4[i] = make_float4(x, y, z, fmaf(x, x, fmaf(y, y, z * z)));
    }
}

// Pass 1: NSTR stream minima per (query, chunk); 4 queries per thread so each
// 12-cyc ds_read_b128 feeds ~40 cyc of VALU (LDS pipe was the bottleneck).
__global__ __launch_bounds__(256) void knn_tau_kernel(const float4* __restrict__ pos4,
                                                      float* __restrict__ minpart) {
    int tid = threadIdx.x;
    int q0 = blockIdx.x * 1024 + tid;
    int c = blockIdx.y;
    float4 qa = pos4[q0];
    float4 qb = pos4[q0 + 256];
    float4 qc = pos4[q0 + 512];
    float4 qd = pos4[q0 + 768];
    float mna[NSTR], mnb[NSTR], mnc[NSTR], mnd[NSTR];
#pragma unroll
    for (int u = 0; u < NSTR; ++u) { mna[u] = INFINITY; mnb[u] = INFINITY; mnc[u] = INFINITY; mnd[u] = INFINITY; }
    __shared__ float4 tile[256];
    int base = c * CHUNK_T;
    for (int t0 = 0; t0 < CHUNK_T; t0 += 256) {
        __syncthreads();
        tile[tid] = pos4[base + t0 + tid];
        __syncthreads();
        for (int jj = 0; jj < 256; jj += NSTR) {
#pragma unroll
            for (int u = 0; u < NSTR; ++u) {
                float4 p = tile[jj + u];
                mna[u] = fminf(mna[u], distf(qa, p));
                mnb[u] = fminf(mnb[u], distf(qb, p));
                mnc[u] = fminf(mnc[u], distf(qc, p));
                mnd[u] = fminf(mnd[u], distf(qd, p));
            }
        }
    }
#pragma unroll
    for (int u = 0; u < NSTR; ++u) {
        minpart[(c * NSTR + u) * NPTS + q0] = mna[u];
        minpart[(c * NSTR + u) * NPTS + q0 + 256] = mnb[u];
        minpart[(c * NSTR + u) * NPTS + q0 + 512] = mnc[u];
        minpart[(c * NSTR + u) * NPTS + q0 + 768] = mnd[u];
    }
}

// tau[q] = max over the 16 global stream minima; >= d_16(q) (16 distinct argmins).
__global__ __launch_bounds__(256) void knn_tau_reduce_kernel(const float* __restrict__ minpart,
                                                             float* __restrict__ tau) {
    int q = blockIdx.x * 256 + threadIdx.x;
    float t = -INFINITY;
#pragma unroll
    for (int u = 0; u < NSTR; ++u) {
        float m = INFINITY;
#pragma unroll
        for (int c = 0; c < CHUNKS_T; ++c) m = fminf(m, minpart[(c * NSTR + u) * NPTS + q]);
        t = fmaxf(t, m);
    }
    tau[q] = t;
}

// Pass 2: record tau-survivor indices per (query, chunk); 4 queries/thread.
__global__ __launch_bounds__(256) void knn_survey_kernel(const float4* __restrict__ pos4,
                                                         const float* __restrict__ tau,
                                                         int* __restrict__ surv,
                                                         int* __restrict__ cnt,
                                                         int* __restrict__ flags) {
    int tid = threadIdx.x;
    int q0 = blockIdx.x * 1024 + tid;
    int q1 = q0 + 256, q2 = q0 + 512, q3 = q0 + 768;
    int c = blockIdx.y;
    float4 qa = pos4[q0], qb = pos4[q1], qc = pos4[q2], qd = pos4[q3];
    float ta = tau[q0], tb = tau[q1], tc = tau[q2], td = tau[q3];
    __shared__ float4 tile[256];
    int base = c * CHUNK_S;
    int ca = 0, cb = 0, cc = 0, cd = 0;
    int sba = (q0 * CHUNKS_S + c) * CAPS;
    int sbb = (q1 * CHUNKS_S + c) * CAPS;
    int sbc = (q2 * CHUNKS_S + c) * CAPS;
    int sbd = (q3 * CHUNKS_S + c) * CAPS;
    for (int t0 = 0; t0 < CHUNK_S; t0 += 256) {
        __syncthreads();
        tile[tid] = pos4[base + t0 + tid];
        __syncthreads();
#pragma unroll 4
        for (int jj = 0; jj < 256; ++jj) {
            float4 p = tile[jj];
            int j = base + t0 + jj;
            float va = distf(qa, p);
            float vb = distf(qb, p);
            float vc = distf(qc, p);
            float vd = distf(qd, p);
            if (va <= ta) { if (ca < CAPS) surv[sba + ca] = j; ++ca; }
            if (vb <= tb) { if (cb < CAPS) surv[sbb + cb] = j; ++cb; }
            if (vc <= tc) { if (cc < CAPS) surv[sbc + cc] = j; ++cc; }
            if (vd <= td) { if (cd < CAPS) surv[sbd + cd] = j; ++cd; }
        }
    }
    cnt[c * NPTS + q0] = ca;
    cnt[c * NPTS + q1] = cb;
    cnt[c * NPTS + q2] = cc;
    cnt[c * NPTS + q3] = cd;
    if (ca > CAPS) flags[q0] = 1;
    if (cb > CAPS) flags[q1] = 1;
    if (cc > CAPS) flags[q2] = 1;
    if (cd > CAPS) flags[q3] = 1;
}

// Pass 3: ONE WAVE PER QUERY. All 384 survivor slots loaded in parallel across
// lanes; exact top-16 via packed-u64 wave merge.
__global__ __launch_bounds__(256) void knn_final_kernel(const float4* __restrict__ pos4,
                                                        const int* __restrict__ surv,
                                                        const int* __restrict__ cnt,
                                                        const int* __restrict__ flags,
                                                        const float* __restrict__ tau,
                                                        int* __restrict__ idx) {
    int lane = threadIdx.x & 63;
    int q = blockIdx.x * 4 + (threadIdx.x >> 6);
    float4 qp = pos4[q];
    if (flags[q] == 0) {
        int c = lane & 31;
        int sb = lane >> 5;                 // 0 or 1
        int n = cnt[c * NPTS + q];
        int sbase = (q * CHUNKS_S + c) * CAPS;
        unsigned long long key[6];
#pragma unroll
        for (int r = 0; r < 6; ++r) {
            int s = sb + 2 * r;             // slots 0..11
            key[r] = ~0ull;
            if (s < n) {
                int j = surv[sbase + s];
                key[r] = dkey(distf(qp, pos4[j]), j);
            }
        }
        wave_top16<6>(key, lane, q, idx);
    } else {
        // overflow slow path: wave-cooperative exact rescan (expected ~never)
        float tq = tau[q];
        unsigned long long key[16];
#pragma unroll
        for (int u = 0; u < 16; ++u) key[u] = ~0ull;
        for (int j = lane; j < NPTS; j += 64) {
            float v = distf(qp, pos4[j]);
            unsigned long long k = dkey(v, j);
            if (v <= tq && k < key[15]) {
#pragma unroll
                for (int s = 0; s < 16; ++s) {
                    unsigned long long mn = k < key[s] ? k : key[s];
                    unsigned long long mx = k < key[s] ? key[s] : k;
                    key[s] = mn;
                    k = mx;
                }
            }
        }
        wave_top16<16>(key, lane, q, idx);
    }
}

// EdgeConv factorization: m[k][t] = C[i][t] + Y[j][t] with Y depending only on j.
// max over k commutes with the +C shift -> per-point precompute + gather-max.

// ec1_pre: C1[p][t] = b1 + xi·(W1a-W1b) ; Y1[p][t] = xp·W1b  (p as neighbor)
__global__ __launch_bounds__(256) void ec1_pre_kernel(const float4* __restrict__ pos4,
                                                      const float* __restrict__ W1,
                                                      const float* __restrict__ b1,
                                                      float* __restrict__ C1,
                                                      float* __restrict__ Y1) {
    int t = threadIdx.x & 63;
    int p = blockIdx.x * 4 + (threadIdx.x >> 6);
    float4 x = pos4[p];
    float w0 = W1[0 * HID + t], w1 = W1[1 * HID + t], w2 = W1[2 * HID + t];
    float v0 = W1[3 * HID + t], v1 = W1[4 * HID + t], v2 = W1[5 * HID + t];
    float y = fmaf(x.x, v0, fmaf(x.y, v1, x.z * v2));
    float cc = b1[t] + x.x * (w0 - v0) + x.y * (w1 - v1) + x.z * (w2 - v2);
    Y1[p * HID + t] = y;
    C1[p * HID + t] = cc;
}

// ec1_max: h1[p][t] = relu(C1[p][t] + max_k Y1[idx[p][k]][t])
__global__ __launch_bounds__(256) void ec1_max_kernel(const float* __restrict__ C1,
                                                      const float* __restrict__ Y1,
                                                      const int* __restrict__ idx,
                                                      float* __restrict__ h1) {
    int t = threadIdx.x & 63;
    int p = blockIdx.x * 4 + (threadIdx.x >> 6);
    float m = -INFINITY;
#pragma unroll
    for (int k = 0; k < KNN; ++k) {
        int j = idx[p * KNN + k];
        m = fmaxf(m, Y1[j * HID + t]);
    }
    h1[p * HID + t] = fmaxf(C1[p * HID + t] + m, 0.f);
}

// ec2_pre: C2[p][t] = b2 + h1[p]·(W2a-W2b) ; Y2[p][t] = h1[p]·W2b
// 4 points per thread to amortize the W2 column loads.
__global__ __launch_bounds__(256) void ec2_pre_kernel(const float* __restrict__ h1,
                                                      const float* __restrict__ W2,
                                                      const float* __restrict__ b2,
                                                      float* __restrict__ C2,
                                                      float* __restrict__ Y2) {
    int t = threadIdx.x & 63;
    int r = threadIdx.x >> 6;            // 0..3
    int pb = blockIdx.x * 16 + r * 4;
    float aa[4] = {0.f, 0.f, 0.f, 0.f};
    float ab[4] = {0.f, 0.f, 0.f, 0.f};
#pragma unroll 8
    for (int f = 0; f < 64; ++f) {
        float wa = W2[f * HID + t];
        float wb = W2[(64 + f) * HID + t];
#pragma unroll
        for (int i = 0; i < 4; ++i) {
            float h = h1[(pb + i) * HID + f];   // wave-uniform broadcast
            aa[i] = fmaf(h, wa, aa[i]);
            ab[i] = fmaf(h, wb, ab[i]);
        }
    }
    float bt = b2[t];
#pragma unroll
    for (int i = 0; i < 4; ++i) {
        C2[(pb + i) * HID + t] = bt + aa[i] - ab[i];
        Y2[(pb + i) * HID + t] = ab[i];
    }
}

// ec2_maxpool: val = relu(C2 + max_k Y2[idx[k]]); block-partial max-pool.
__global__ __launch_bounds__(256) void ec2_maxpool_kernel(const float* __restrict__ C2,
                                                          const float* __restrict__ Y2,
                                                          const int* __restrict__ idx,
                                                          float* __restrict__ gpartial) {
    int t = threadIdx.x & 63;
    int lp = threadIdx.x >> 6;
    int p = blockIdx.x * 4 + lp;
    float m = -INFINITY;
#pragma unroll
    for (int k = 0; k < KNN; ++k) {
        int j = idx[p * KNN + k];
        m = fmaxf(m, Y2[j * HID + t]);
    }
    float val = fmaxf(C2[p * HID + t] + m, 0.f);
    __shared__ float red[4][64];
    red[lp][t] = val;
    __syncthreads();
    if (lp == 0) {
        float g = fmaxf(fmaxf(red[0][t], red[1][t]), fmaxf(red[2][t], red[3][t]));
        gpartial[blockIdx.x * 64 + t] = g;
    }
}

__global__ void greduce_kernel(const float* __restrict__ gpartial, float* __restrict__ g, int nb) {
    int f = blockIdx.x;
    float m = -INFINITY;
    for (int i = threadIdx.x; i < nb; i += 256) m = fmaxf(m, gpartial[i * 64 + f]);
    __shared__ float s[256];
    s[threadIdx.x] = m;
    __syncthreads();
    for (int st = 128; st > 0; st >>= 1) {
        if (threadIdx.x < st) s[threadIdx.x] = fmaxf(s[threadIdx.x], s[threadIdx.x + st]);
        __syncthreads();
    }
    if (threadIdx.x == 0) g[f] = s[0];
}

__global__ void head_kernel(const float* __restrict__ g, const float* __restrict__ Wc,
                            const float* __restrict__ bc, float* __restrict__ out) {
    int c = threadIdx.x;
    if (c < NCLS) {
        float a = bc[c];
#pragma unroll
        for (int h = 0; h < HID; ++h) a = fmaf(g[h], Wc[h * NCLS + c], a);
        out[c] = a;
    }
}

extern "C" void kernel_launch(void* const* d_in, const int* in_sizes, int n_in,
                              void* d_out, int out_size, void* d_ws, size_t ws_size,
                              hipStream_t stream) {
    const float* pos = (const float*)d_in[0];
    // d_in[1] = batch (all zeros, num_segments=1) -> unused
    const float* W1 = (const float*)d_in[2];
    const float* b1 = (const float*)d_in[3];
    const float* W2 = (const float*)d_in[4];
    const float* b2 = (const float*)d_in[5];
    const float* Wc = (const float*)d_in[6];
    const float* bc = (const float*)d_in[7];
    float* out = (float*)d_out;

    char* ws = (char*)d_ws;
    size_t o = 0;
    auto alloc = [&](size_t bytes) { size_t r = o; o += (bytes + 255) & ~size_t(255); return r; };
    size_t sz_minp = (size_t)NPTS * CHUNKS_T * NSTR * 4;      // 16MB
    size_t sz_surv = (size_t)NPTS * CHUNKS_S * CAPS * 4;      // 24MB
    size_t o_pos4 = alloc((size_t)NPTS * 16);
    size_t o_shared = alloc(sz_minp > sz_surv ? sz_minp : sz_surv);  // minp -> surv -> C/Y
    size_t o_tau = alloc((size_t)NPTS * 4);
    size_t o_cnt = alloc((size_t)NPTS * CHUNKS_S * 4);
    size_t o_flag = alloc((size_t)NPTS * 4);
    size_t o_idx = alloc((size_t)NPTS * KNN * 4);
    size_t o_h1 = alloc((size_t)NPTS * HID * 4);
    size_t o_gp = alloc((size_t)(NPTS / 4) * HID * 4);
    size_t o_g = alloc(256);

    float4* pos4 = (float4*)(ws + o_pos4);
    float* minp = (float*)(ws + o_shared);
    int* surv = (int*)(ws + o_shared);    // overlays minp (dead after tau_reduce)
    // C1/Y1/C2/Y2 overlay surv (dead after knn_final): 4 x 4MB <= 24MB region
    size_t fm = (size_t)NPTS * HID * 4;
    float* C1 = (float*)(ws + o_shared + 0 * fm);
    float* Y1 = (float*)(ws + o_shared + 1 * fm);
    float* C2 = (float*)(ws + o_shared + 2 * fm);
    float* Y2 = (float*)(ws + o_shared + 3 * fm);
    float* tau = (float*)(ws + o_tau);
    int* cnt = (int*)(ws + o_cnt);
    int* flags = (int*)(ws + o_flag);
    int* idx = (int*)(ws + o_idx);
    float* h1 = (float*)(ws + o_h1);
    float* gp = (float*)(ws + o_gp);
    float* g = (float*)(ws + o_g);

    hipMemsetAsync(flags, 0, (size_t)NPTS * 4, stream);

    prep_kernel<<<NPTS / 256, 256, 0, stream>>>(pos, pos4);
    knn_tau_kernel<<<dim3(NPTS / 1024, CHUNKS_T), 256, 0, stream>>>(pos4, minp);
    knn_tau_reduce_kernel<<<NPTS / 256, 256, 0, stream>>>(minp, tau);
    knn_survey_kernel<<<dim3(NPTS / 1024, CHUNKS_S), 256, 0, stream>>>(pos4, tau, surv, cnt, flags);
    knn_final_kernel<<<NPTS / 4, 256, 0, stream>>>(pos4, surv, cnt, flags, tau, idx);
    ec1_pre_kernel<<<NPTS / 4, 256, 0, stream>>>(pos4, W1, b1, C1, Y1);
    ec1_max_kernel<<<NPTS / 4, 256, 0, stream>>>(C1, Y1, idx, h1);
    ec2_pre_kernel<<<NPTS / 16, 256, 0, stream>>>(h1, W2, b2, C2, Y2);
    ec2_maxpool_kernel<<<NPTS / 4, 256, 0, stream>>>(C2, Y2, idx, gp);
    greduce_kernel<<<HID, 256, 0, stream>>>(gp, g, NPTS / 4);
    head_kernel<<<1, 64, 0, stream>>>(g, Wc, bc, out);
}